// Round 1
// baseline (660.850 us; speedup 1.0000x reference)
//
#include <hip/hip_runtime.h>

// Problem constants (fixed by reference setup_inputs):
//   inputs: [8192, 64] f32, rand: [8192, 64] f32
//   capacity = max(ceil(1.25 * 8192 / 64), 4) = 160
#define S 8192
#define E 64
#define CAP 160
static constexpr long long COMB = (long long)S * E * CAP;  // 83,886,080 elements

// --- Kernel 1: per-token router ------------------------------------------
// One wave (64 lanes) per token. Lane l holds logits[token][l] and
// rand[token][l]. Computes:
//   argmax (lowest-index tiebreak, matching jnp.argmax)
//   prob at argmax = exp(0) / sum exp(x - max) = 1 / sum
//   rand value at argmax column
__global__ __launch_bounds__(256) void router_kernel(
    const float* __restrict__ x, const float* __restrict__ rnd,
    int* __restrict__ eidx, float* __restrict__ prob, float* __restrict__ rv)
{
    const int token = blockIdx.x * 4 + (threadIdx.x >> 6);
    const int lane  = threadIdx.x & 63;

    const float v = x[token * E + lane];
    const float r = rnd[token * E + lane];

    // butterfly (max, min-index) reduction — associative+commutative, so
    // every lane ends with the full-wave argmax
    float m = v; int ai = lane;
    #pragma unroll
    for (int off = 32; off; off >>= 1) {
        float m2 = __shfl_xor(m, off, 64);
        int   i2 = __shfl_xor(ai, off, 64);
        if (m2 > m || (m2 == m && i2 < ai)) { m = m2; ai = i2; }
    }

    float s = expf(v - m);
    #pragma unroll
    for (int off = 32; off; off >>= 1) s += __shfl_xor(s, off, 64);

    const float ra = __shfl(r, ai, 64);  // rand value at the argmax column

    if (lane == 0) {
        eidx[token] = ai;
        prob[token] = 1.0f / s;
        rv[token]   = ra;
    }
}

// --- Kernel 2: per-expert capacity selection + scatter --------------------
// One block (256 threads = 4 waves) per expert.
// Phase 1: count tokens assigned to this expert.
// Phase 2: scan tokens in index order; kept tokens get loc = running rank
//          (reference's cumsum(dispatch_mask) - 1). If count > capacity
//          (never true for this input: max count = 152 < 160), fall back to
//          exact top-k-by-rand selection with (rand desc, index asc) order,
//          matching jax.lax.top_k tiebreak.
__global__ __launch_bounds__(256) void dispatch_kernel(
    const int* __restrict__ eidx, const float* __restrict__ prob,
    const float* __restrict__ rv, float* __restrict__ out)
{
    const int e    = blockIdx.x;
    const int lane = threadIdx.x & 63;
    const int wave = threadIdx.x >> 6;

    __shared__ int s_count;
    __shared__ int s_run;
    __shared__ int wcnt[4];

    if (threadIdx.x == 0) { s_count = 0; s_run = 0; }
    __syncthreads();

    // Phase 1: count assigned tokens
    int local = 0;
    for (int t = threadIdx.x; t < S; t += 256) local += (eidx[t] == e);
    #pragma unroll
    for (int off = 32; off; off >>= 1) local += __shfl_xor(local, off, 64);
    if (lane == 0) atomicAdd(&s_count, local);
    __syncthreads();
    const int count = s_count;

    // Phase 2: index-ordered scan with block prefix-sum for loc
    for (int base = 0; base < S; base += 256) {
        const int t = base + threadIdx.x;
        const bool match = (eidx[t] == e);
        bool kept = match;
        if (match && count > CAP) {
            // general fallback: kept iff fewer than CAP assigned tokens rank
            // strictly better by (rand desc, index asc)
            int better = 0;
            const float rt = rv[t];
            for (int j = 0; j < S; ++j) {
                if (eidx[j] == e) {
                    const float rj = rv[j];
                    if (rj > rt || (rj == rt && j < t)) better++;
                }
            }
            kept = (better < CAP);
        }

        const unsigned long long bm = __ballot(kept);
        if (lane == 0) wcnt[wave] = __popcll(bm);
        __syncthreads();

        int loc = s_run + __popcll(bm & ((1ULL << lane) - 1ULL));
        for (int w = 0; w < wave; ++w) loc += wcnt[w];

        if (kept) {
            const long long p = ((long long)t * E + e) * CAP + loc;
            out[p]        = prob[t];   // combine_weights
            out[COMB + p] = 1.0f;      // sec_mask (bool -> 1.0f)
        }
        __syncthreads();
        if (threadIdx.x == 0) s_run += wcnt[0] + wcnt[1] + wcnt[2] + wcnt[3];
        __syncthreads();  // protect wcnt/s_run before next iteration
    }

    if (threadIdx.x == 0) out[2 * COMB + e] = (float)count;  // exp_counts
}

extern "C" void kernel_launch(void* const* d_in, const int* in_sizes, int n_in,
                              void* d_out, int out_size, void* d_ws, size_t ws_size,
                              hipStream_t stream)
{
    const float* inputs = (const float*)d_in[0];
    const float* rnd    = (const float*)d_in[1];
    float* out = (float*)d_out;

    // workspace layout: eidx[S] int32 | prob[S] f32 | rv[S] f32  (96 KB)
    int*   eidx = (int*)d_ws;
    float* prob = (float*)((char*)d_ws + (size_t)S * sizeof(int));
    float* rv   = (float*)((char*)d_ws + (size_t)S * (sizeof(int) + sizeof(float)));

    // Zero the (poisoned) 671 MB output — the dominant, HBM-write-bound cost.
    hipMemsetAsync(d_out, 0, (size_t)out_size * sizeof(float), stream);

    router_kernel<<<S / 4, 256, 0, stream>>>(inputs, rnd, eidx, prob, rv);
    dispatch_kernel<<<E, 256, 0, stream>>>(eidx, prob, rv, out);
}

// Round 3
// 660.753 us; speedup vs baseline: 1.0001x; 1.0001x over previous
//
#include <hip/hip_runtime.h>

// Problem constants (fixed by reference setup_inputs):
//   inputs: [8192, 64] f32, rand: [8192, 64] f32
//   capacity = max(ceil(1.25 * 8192 / 64), 4) = 160
#define S 8192
#define E 64
#define CAP 160
#define ROW (E * CAP)                       // 10240 floats per token row
#define NCHUNK (S / 256)                    // 32 chunks of 256 tokens
static constexpr long long COMB = (long long)S * E * CAP;  // 83,886,080

typedef float f32x4 __attribute__((ext_vector_type(4)));

// --- Kernel 1: per-token router (one wave per token) ----------------------
// argmax (lowest-index tiebreak, matching jnp.argmax), softmax prob at the
// argmax = 1/sum(exp(x-max)), and rand value at the argmax column.
__global__ __launch_bounds__(256) void router_kernel(
    const float* __restrict__ x, const float* __restrict__ rnd,
    int* __restrict__ eidx, float* __restrict__ prob, float* __restrict__ rv)
{
    const int token = blockIdx.x * 4 + (threadIdx.x >> 6);
    const int lane  = threadIdx.x & 63;

    const float v = x[token * E + lane];
    const float r = rnd[token * E + lane];

    float m = v; int ai = lane;
    #pragma unroll
    for (int off = 32; off; off >>= 1) {
        float m2 = __shfl_xor(m, off, 64);
        int   i2 = __shfl_xor(ai, off, 64);
        if (m2 > m || (m2 == m && i2 < ai)) { m = m2; ai = i2; }
    }

    float s = expf(v - m);
    #pragma unroll
    for (int off = 32; off; off >>= 1) s += __shfl_xor(s, off, 64);

    const float ra = __shfl(r, ai, 64);

    if (lane == 0) {
        eidx[token] = ai;
        prob[token] = 1.0f / s;
        rv[token]   = ra;
    }
}

// --- Kernel 2: per-chunk expert histogram (32 blocks) ---------------------
__global__ __launch_bounds__(256) void hist_kernel(
    const int* __restrict__ eidx, int* __restrict__ chunk_hist)
{
    __shared__ int h[E];
    const int b = blockIdx.x;
    if (threadIdx.x < E) h[threadIdx.x] = 0;
    __syncthreads();
    atomicAdd(&h[eidx[b * 256 + threadIdx.x]], 1);
    __syncthreads();
    if (threadIdx.x < E) chunk_hist[b * E + threadIdx.x] = h[threadIdx.x];
}

// --- Kernel 3: slot assignment (32 blocks) --------------------------------
// loc[t] = rank of token t among same-expert tokens by index
//        = (prefix over earlier chunks) + (rank within chunk).
// Writes ofs[t] = e*CAP + loc (or -1 if dropped), counts[e].
// Overflow fallback (count > CAP, NOT triggered for this input: max 152)
// reproduces jax.lax.top_k's (rand desc, index asc) selection exactly.
__global__ __launch_bounds__(256) void rank_kernel(
    const int* __restrict__ eidx, const float* __restrict__ rv,
    const int* __restrict__ chunk_hist,
    int* __restrict__ ofs, int* __restrict__ counts_g)
{
    const int b   = blockIdx.x;
    const int tid = threadIdx.x;
    __shared__ int base[E];
    __shared__ int tot[E];
    __shared__ int le[256];

    if (tid < E) {
        int pre = 0, tt = 0;
        for (int c = 0; c < NCHUNK; ++c) {
            const int v = chunk_hist[c * E + tid];
            if (c < b) pre += v;
            tt += v;
        }
        base[tid] = pre; tot[tid] = tt;
        if (b == 0) counts_g[tid] = tt;
    }
    const int t = b * 256 + tid;
    const int e = eidx[t];
    le[tid] = e;
    __syncthreads();

    int rank = 0;
    for (int j = 0; j < tid; ++j) rank += (le[j] == e);
    int loc = base[e] + rank;

    bool kept = true;
    if (tot[e] > CAP) {   // guarded slow path; never taken for this input
        const float rt = rv[t];
        int better = 0;
        for (int j = 0; j < S; ++j)
            if (eidx[j] == e) {
                const float rj = rv[j];
                if (rj > rt || (rj == rt && j < t)) better++;
            }
        kept = (better < CAP);
        if (kept) {
            int l = 0;
            for (int j = 0; j < t; ++j)
                if (eidx[j] == e) {
                    const float rj = rv[j];
                    int bj = 0;
                    for (int k = 0; k < S; ++k)
                        if (eidx[k] == e) {
                            const float rk = rv[k];
                            if (rk > rj || (rk == rj && k < j)) bj++;
                        }
                    if (bj < CAP) l++;
                }
            loc = l;
        }
    }
    ofs[t] = kept ? (e * CAP + loc) : -1;
}

// --- Kernel 4: fused zero-fill + scatter ----------------------------------
// One block per token row. Writes every output byte exactly once:
//   combine_weights[t, :, :] (10240 f32) with prob at column ofs[t],
//   sec_mask[t, :, :]        (10240 f32) with 1.0 at column ofs[t],
//   block 0 additionally writes exp_counts[64].
// Fully coalesced float4 non-temporal stores — pure HBM-write-bound.
__global__ __launch_bounds__(256) void fill_scatter_kernel(
    const int* __restrict__ ofs, const float* __restrict__ prob,
    const int* __restrict__ counts, float* __restrict__ out)
{
    const int t   = blockIdx.x;
    const int tid = threadIdx.x;
    const int o   = ofs[t];      // wave-uniform L1 broadcast
    const float v = prob[t];

    f32x4* __restrict__ dst0 = (f32x4*)(out + (size_t)t * ROW);
    f32x4* __restrict__ dst1 = (f32x4*)(out + (size_t)COMB + (size_t)t * ROW);

    #pragma unroll
    for (int k = 0; k < ROW / 4 / 256; ++k) {   // 10 iterations
        const int c4  = k * 256 + tid;
        const int col = c4 * 4;
        f32x4 z0, z1;
        z0.x = (o == col + 0) ? v : 0.0f;  z1.x = (o == col + 0) ? 1.0f : 0.0f;
        z0.y = (o == col + 1) ? v : 0.0f;  z1.y = (o == col + 1) ? 1.0f : 0.0f;
        z0.z = (o == col + 2) ? v : 0.0f;  z1.z = (o == col + 2) ? 1.0f : 0.0f;
        z0.w = (o == col + 3) ? v : 0.0f;  z1.w = (o == col + 3) ? 1.0f : 0.0f;
        __builtin_nontemporal_store(z0, &dst0[c4]);
        __builtin_nontemporal_store(z1, &dst1[c4]);
    }

    if (t == 0 && tid < E)
        out[2 * COMB + tid] = (float)counts[tid];
}

extern "C" void kernel_launch(void* const* d_in, const int* in_sizes, int n_in,
                              void* d_out, int out_size, void* d_ws, size_t ws_size,
                              hipStream_t stream)
{
    const float* inputs = (const float*)d_in[0];
    const float* rnd    = (const float*)d_in[1];
    float* out = (float*)d_out;

    // workspace layout (all int32/f32, S=8192):
    //   eidx[S] | prob[S] | rv[S] | ofs[S] | chunk_hist[32*64] | counts[64]
    char* w = (char*)d_ws;
    int*   eidx  = (int*)w;                          w += S * 4;
    float* prob  = (float*)w;                        w += S * 4;
    float* rv    = (float*)w;                        w += S * 4;
    int*   ofs   = (int*)w;                          w += S * 4;
    int*   chist = (int*)w;                          w += NCHUNK * E * 4;
    int*   cnts  = (int*)w;

    router_kernel<<<S / 4, 256, 0, stream>>>(inputs, rnd, eidx, prob, rv);
    hist_kernel<<<NCHUNK, 256, 0, stream>>>(eidx, chist);
    rank_kernel<<<NCHUNK, 256, 0, stream>>>(eidx, rv, chist, ofs, cnts);
    fill_scatter_kernel<<<S, 256, 0, stream>>>(ofs, prob, cnts, out);
}